// Round 1
// baseline (1024.010 us; speedup 1.0000x reference)
//
#include <hip/hip_runtime.h>

#define N_NODES 100000
#define N_EDGES 1600000
#define F 64

// outdeg histogram: needed for the layer-3 algebraic reduction
// sum_i aggr3_i = sum_j outdeg(j) * h2_j
__global__ void outdeg_kernel(const int* __restrict__ edges, int* __restrict__ outdeg) {
    int e = blockIdx.x * 256 + threadIdx.x;
    if (e < N_EDGES) atomicAdd(&outdeg[edges[e]], 1);
}

// wave-per-edge scatter: lane = feature. Coalesced 256B gather of feat[src],
// 64 consecutive-address f32 atomics into aggr[dst].
__global__ void scatter_kernel(const float* __restrict__ feat,
                               const int* __restrict__ edges,
                               float* __restrict__ aggr) {
    unsigned long long t = (unsigned long long)blockIdx.x * 256ull + threadIdx.x;
    int e = (int)(t >> 6);
    int f = (int)(t & 63);
    int s = edges[e];
    int d = edges[N_EDGES + e];
    atomicAdd(&aggr[(size_t)d * F + f], feat[(size_t)s * F + f]);
}

// Fused per-node transform: out = [relu](aggr @ w_rel + b_rel + x @ w_root)
// block = 256 threads -> 64 nodes; inputs staged in LDS; lane = out feature,
// each thread accumulates 16 nodes; LDS reads are wave-broadcast float4.
__global__ void transform_kernel(const float* __restrict__ aggr,
                                 const float* __restrict__ xin,
                                 const float* __restrict__ w_rel,
                                 const float* __restrict__ b_rel,
                                 const float* __restrict__ w_root,
                                 float* __restrict__ out,
                                 const int do_relu) {
    __shared__ float sA[64 * F];
    __shared__ float sX[64 * F];
    const int node0 = blockIdx.x * 64;
    float4* s4A = (float4*)sA;
    float4* s4X = (float4*)sX;
    const float4* gA = (const float4*)(aggr + (size_t)node0 * F);
    const float4* gX = (const float4*)(xin + (size_t)node0 * F);
    for (int k = threadIdx.x; k < 64 * F / 4; k += 256) {
        int node = node0 + (k >> 4);
        float4 a = make_float4(0.f, 0.f, 0.f, 0.f);
        float4 x = a;
        if (node < N_NODES) { a = gA[k]; x = gX[k]; }
        s4A[k] = a;
        s4X[k] = x;
    }
    __syncthreads();

    const int fp = threadIdx.x & 63;   // output feature
    const int grp = threadIdx.x >> 6;  // node sub-group 0..3
    float acc[16];
    const float bias = b_rel[fp];
#pragma unroll
    for (int k = 0; k < 16; k++) acc[k] = bias;

    for (int f = 0; f < F; f += 4) {
        float wr0 = w_rel[(f + 0) * F + fp];
        float wr1 = w_rel[(f + 1) * F + fp];
        float wr2 = w_rel[(f + 2) * F + fp];
        float wr3 = w_rel[(f + 3) * F + fp];
        float wo0 = w_root[(f + 0) * F + fp];
        float wo1 = w_root[(f + 1) * F + fp];
        float wo2 = w_root[(f + 2) * F + fp];
        float wo3 = w_root[(f + 3) * F + fp];
#pragma unroll
        for (int k = 0; k < 16; k++) {
            int n = grp * 16 + k;
            float4 a = *(const float4*)&sA[n * F + f];
            float4 x = *(const float4*)&sX[n * F + f];
            acc[k] += a.x * wr0 + a.y * wr1 + a.z * wr2 + a.w * wr3
                    + x.x * wo0 + x.y * wo1 + x.z * wo2 + x.w * wo3;
        }
    }
#pragma unroll
    for (int k = 0; k < 16; k++) {
        int n = grp * 16 + k;
        int node = node0 + n;
        if (node < N_NODES) {
            float v = acc[k];
            if (do_relu) v = fmaxf(v, 0.0f);
            out[(size_t)node * F + fp] = v;
        }
    }
}

// S[0:64]  = sum_i outdeg(i) * h2[i][:]
// S[64:128]= sum_i h2[i][:]
__global__ void reduce_kernel(const float* __restrict__ h,
                              const int* __restrict__ outdeg,
                              float* __restrict__ S) {
    const int f = threadIdx.x & 63;
    const int grp = threadIdx.x >> 6;
    float a1 = 0.f, a2 = 0.f;
    for (int i = blockIdx.x * 4 + grp; i < N_NODES; i += gridDim.x * 4) {
        float deg = (float)outdeg[i];
        float v = h[(size_t)i * F + f];
        a1 += deg * v;
        a2 += v;
    }
    atomicAdd(&S[f], a1);
    atomicAdd(&S[64 + f], a2);
}

// out = mean_i(h3_i) = (S1 . w_rel3 + N*b3 + S2 . w_root3) / N
__global__ void final_kernel(const float* __restrict__ S,
                             const float* __restrict__ w_rel3,
                             const float* __restrict__ b_rel3,
                             const float* __restrict__ w_root3,
                             float* __restrict__ out) {
    int f = threadIdx.x;  // 64 threads, one wave
    float v = S[f] * w_rel3[f] + S[64 + f] * w_root3[f];
    for (int off = 32; off > 0; off >>= 1) v += __shfl_down(v, off);
    if (f == 0) out[0] = v * (1.0f / (float)N_NODES) + b_rel3[0];
}

extern "C" void kernel_launch(void* const* d_in, const int* in_sizes, int n_in,
                              void* d_out, int out_size, void* d_ws, size_t ws_size,
                              hipStream_t stream) {
    const float* x       = (const float*)d_in[0];
    const int*   edges   = (const int*)d_in[1];   // [2, E]: src row then dst row
    const float* w_rel1  = (const float*)d_in[2];
    const float* b_rel1  = (const float*)d_in[3];
    const float* w_root1 = (const float*)d_in[4];
    const float* w_rel2  = (const float*)d_in[5];
    const float* b_rel2  = (const float*)d_in[6];
    const float* w_root2 = (const float*)d_in[7];
    const float* w_rel3  = (const float*)d_in[8];
    const float* b_rel3  = (const float*)d_in[9];
    const float* w_root3 = (const float*)d_in[10];
    float* out = (float*)d_out;

    const size_t nf = (size_t)N_NODES * F;
    float* aggr = (float*)d_ws;
    float* h1 = aggr + nf;
    float* h2 = h1 + nf;
    float* S = h2 + nf;
    int* outdeg = (int*)(S + 128);

    hipMemsetAsync(aggr, 0, nf * sizeof(float), stream);
    hipMemsetAsync(S, 0, 128 * sizeof(float), stream);
    hipMemsetAsync(outdeg, 0, N_NODES * sizeof(int), stream);

    outdeg_kernel<<<(N_EDGES + 255) / 256, 256, 0, stream>>>(edges, outdeg);

    // layer 1
    scatter_kernel<<<(unsigned)((size_t)N_EDGES * 64 / 256), 256, 0, stream>>>(x, edges, aggr);
    transform_kernel<<<(N_NODES + 63) / 64, 256, 0, stream>>>(aggr, x, w_rel1, b_rel1, w_root1, h1, 1);

    // layer 2
    hipMemsetAsync(aggr, 0, nf * sizeof(float), stream);
    scatter_kernel<<<(unsigned)((size_t)N_EDGES * 64 / 256), 256, 0, stream>>>(h1, edges, aggr);
    transform_kernel<<<(N_NODES + 63) / 64, 256, 0, stream>>>(aggr, h1, w_rel2, b_rel2, w_root2, h2, 1);

    // layer 3 collapsed to reductions
    reduce_kernel<<<512, 256, 0, stream>>>(h2, outdeg, S);
    final_kernel<<<1, 64, 0, stream>>>(S, w_rel3, b_rel3, w_root3, out);
}

// Round 2
// 916.554 us; speedup vs baseline: 1.1172x; 1.1172x over previous
//
#include <hip/hip_runtime.h>

#define N_NODES 100000
#define N_EDGES 1600000
#define F 64

// One pass over edges: outdeg[src]++ (for the layer-3 algebraic trick),
// indeg[dst]++ (for CSR row_ptr).
__global__ void degree_kernel(const int* __restrict__ edges,
                              int* __restrict__ outdeg,
                              int* __restrict__ indeg) {
    int e = blockIdx.x * 256 + threadIdx.x;
    if (e < N_EDGES) {
        atomicAdd(&outdeg[edges[e]], 1);
        atomicAdd(&indeg[edges[N_EDGES + e]], 1);
    }
}

// Single-block exclusive scan of indeg -> row_ptr[N+1]; also seeds cursor.
__global__ void scan_kernel(const int* __restrict__ indeg,
                            int* __restrict__ row_ptr,
                            int* __restrict__ cursor) {
    __shared__ int partial[1024];
    const int T = 1024;
    const int tid = threadIdx.x;
    const int chunk = (N_NODES + T - 1) / T;  // 98
    const int start = tid * chunk;
    const int end = min(start + chunk, N_NODES);
    int sum = 0;
    for (int i = start; i < end; i++) sum += indeg[i];
    partial[tid] = sum;
    __syncthreads();
    for (int off = 1; off < T; off <<= 1) {
        int v = (tid >= off) ? partial[tid - off] : 0;
        __syncthreads();
        partial[tid] += v;
        __syncthreads();
    }
    int run = (tid == 0) ? 0 : partial[tid - 1];
    for (int i = start; i < end; i++) {
        row_ptr[i] = run;
        cursor[i] = run;
        run += indeg[i];
    }
    if (tid == T - 1) row_ptr[N_NODES] = run;
}

// col[pos] = src, grouped by dst via atomic cursors. Order within a row is
// arbitrary — fine for a sum.
__global__ void fill_kernel(const int* __restrict__ edges,
                            int* __restrict__ cursor,
                            int* __restrict__ col) {
    int e = blockIdx.x * 256 + threadIdx.x;
    if (e < N_EDGES) {
        int s = edges[e];
        int d = edges[N_EDGES + e];
        int pos = atomicAdd(&cursor[d], 1);
        col[pos] = s;
    }
}

// Atomic-free pull gather: wave-per-node, lane = feature.
// col[e] loads are wave-broadcast (same address); feat row reads are 256B
// coalesced. 2-edge unroll for ILP on the dependent col->feat chain.
__global__ void gather_kernel(const float* __restrict__ feat,
                              const int* __restrict__ row_ptr,
                              const int* __restrict__ col,
                              float* __restrict__ aggr) {
    int node = blockIdx.x * 4 + (threadIdx.x >> 6);
    int f = threadIdx.x & 63;
    if (node >= N_NODES) return;
    int beg = row_ptr[node];
    int end = row_ptr[node + 1];
    float acc = 0.f;
    int e = beg;
    for (; e + 1 < end; e += 2) {
        int s0 = col[e];
        int s1 = col[e + 1];
        float v0 = feat[(size_t)s0 * F + f];
        float v1 = feat[(size_t)s1 * F + f];
        acc += v0;
        acc += v1;
    }
    if (e < end) acc += feat[(size_t)col[e] * F + f];
    aggr[(size_t)node * F + f] = acc;
}

// Fused per-node transform: out = [relu](aggr @ w_rel + b_rel + x @ w_root)
// Row-local per block => out may alias xin (in-place) safely.
__global__ void transform_kernel(const float* __restrict__ aggr,
                                 const float* __restrict__ xin,
                                 const float* __restrict__ w_rel,
                                 const float* __restrict__ b_rel,
                                 const float* __restrict__ w_root,
                                 float* __restrict__ out,
                                 const int do_relu) {
    __shared__ float sA[64 * F];
    __shared__ float sX[64 * F];
    const int node0 = blockIdx.x * 64;
    float4* s4A = (float4*)sA;
    float4* s4X = (float4*)sX;
    const float4* gA = (const float4*)(aggr + (size_t)node0 * F);
    const float4* gX = (const float4*)(xin + (size_t)node0 * F);
    for (int k = threadIdx.x; k < 64 * F / 4; k += 256) {
        int node = node0 + (k >> 4);
        float4 a = make_float4(0.f, 0.f, 0.f, 0.f);
        float4 x = a;
        if (node < N_NODES) { a = gA[k]; x = gX[k]; }
        s4A[k] = a;
        s4X[k] = x;
    }
    __syncthreads();

    const int fp = threadIdx.x & 63;   // output feature
    const int grp = threadIdx.x >> 6;  // node sub-group 0..3
    float acc[16];
    const float bias = b_rel[fp];
#pragma unroll
    for (int k = 0; k < 16; k++) acc[k] = bias;

    for (int f = 0; f < F; f += 4) {
        float wr0 = w_rel[(f + 0) * F + fp];
        float wr1 = w_rel[(f + 1) * F + fp];
        float wr2 = w_rel[(f + 2) * F + fp];
        float wr3 = w_rel[(f + 3) * F + fp];
        float wo0 = w_root[(f + 0) * F + fp];
        float wo1 = w_root[(f + 1) * F + fp];
        float wo2 = w_root[(f + 2) * F + fp];
        float wo3 = w_root[(f + 3) * F + fp];
#pragma unroll
        for (int k = 0; k < 16; k++) {
            int n = grp * 16 + k;
            float4 a = *(const float4*)&sA[n * F + f];
            float4 x = *(const float4*)&sX[n * F + f];
            acc[k] += a.x * wr0 + a.y * wr1 + a.z * wr2 + a.w * wr3
                    + x.x * wo0 + x.y * wo1 + x.z * wo2 + x.w * wo3;
        }
    }
#pragma unroll
    for (int k = 0; k < 16; k++) {
        int n = grp * 16 + k;
        int node = node0 + n;
        if (node < N_NODES) {
            float v = acc[k];
            if (do_relu) v = fmaxf(v, 0.0f);
            out[(size_t)node * F + fp] = v;
        }
    }
}

// S[0:64]  = sum_i outdeg(i) * h2[i][:]   (layer-3 aggr term)
// S[64:128]= sum_i h2[i][:]               (layer-3 root term)
__global__ void reduce_kernel(const float* __restrict__ h,
                              const int* __restrict__ outdeg,
                              float* __restrict__ S) {
    const int f = threadIdx.x & 63;
    const int grp = threadIdx.x >> 6;
    float a1 = 0.f, a2 = 0.f;
    for (int i = blockIdx.x * 4 + grp; i < N_NODES; i += gridDim.x * 4) {
        float deg = (float)outdeg[i];
        float v = h[(size_t)i * F + f];
        a1 += deg * v;
        a2 += v;
    }
    atomicAdd(&S[f], a1);
    atomicAdd(&S[64 + f], a2);
}

// out = mean_i(h3_i) = (S1 . w_rel3 + S2 . w_root3)/N + b3
__global__ void final_kernel(const float* __restrict__ S,
                             const float* __restrict__ w_rel3,
                             const float* __restrict__ b_rel3,
                             const float* __restrict__ w_root3,
                             float* __restrict__ out) {
    int f = threadIdx.x;  // 64 threads, one wave
    float v = S[f] * w_rel3[f] + S[64 + f] * w_root3[f];
    for (int off = 32; off > 0; off >>= 1) v += __shfl_down(v, off);
    if (f == 0) out[0] = v * (1.0f / (float)N_NODES) + b_rel3[0];
}

extern "C" void kernel_launch(void* const* d_in, const int* in_sizes, int n_in,
                              void* d_out, int out_size, void* d_ws, size_t ws_size,
                              hipStream_t stream) {
    const float* x       = (const float*)d_in[0];
    const int*   edges   = (const int*)d_in[1];   // [2, E]: src row then dst row
    const float* w_rel1  = (const float*)d_in[2];
    const float* b_rel1  = (const float*)d_in[3];
    const float* w_root1 = (const float*)d_in[4];
    const float* w_rel2  = (const float*)d_in[5];
    const float* b_rel2  = (const float*)d_in[6];
    const float* w_root2 = (const float*)d_in[7];
    const float* w_rel3  = (const float*)d_in[8];
    const float* b_rel3  = (const float*)d_in[9];
    const float* w_root3 = (const float*)d_in[10];
    float* out = (float*)d_out;

    const size_t nf = (size_t)N_NODES * F;
    float* aggr   = (float*)d_ws;            // 25.6 MB
    float* h1     = aggr + nf;               // 25.6 MB (layer-2 output in-place)
    float* S      = h1 + nf;                 // 512 B
    int*   outdeg = (int*)(S + 128);         // 0.4 MB
    int*   indeg  = outdeg + N_NODES;        // 0.4 MB
    int*   row_ptr= indeg + N_NODES;         // 0.4 MB
    int*   cursor = row_ptr + N_NODES + 1;   // 0.4 MB
    int*   col    = cursor + N_NODES;        // 6.4 MB

    hipMemsetAsync(S, 0, 128 * sizeof(float), stream);
    hipMemsetAsync(outdeg, 0, N_NODES * sizeof(int), stream);
    hipMemsetAsync(indeg, 0, N_NODES * sizeof(int), stream);

    // CSR build (re-done every call; no cross-call state)
    degree_kernel<<<(N_EDGES + 255) / 256, 256, 0, stream>>>(edges, outdeg, indeg);
    scan_kernel<<<1, 1024, 0, stream>>>(indeg, row_ptr, cursor);
    fill_kernel<<<(N_EDGES + 255) / 256, 256, 0, stream>>>(edges, cursor, col);

    const int gather_blocks = (N_NODES + 3) / 4;

    // layer 1
    gather_kernel<<<gather_blocks, 256, 0, stream>>>(x, row_ptr, col, aggr);
    transform_kernel<<<(N_NODES + 63) / 64, 256, 0, stream>>>(aggr, x, w_rel1, b_rel1, w_root1, h1, 1);

    // layer 2 (transform writes h1 in-place; it's row-local per block)
    gather_kernel<<<gather_blocks, 256, 0, stream>>>(h1, row_ptr, col, aggr);
    transform_kernel<<<(N_NODES + 63) / 64, 256, 0, stream>>>(aggr, h1, w_rel2, b_rel2, w_root2, h1, 1);

    // layer 3 collapsed to reductions
    reduce_kernel<<<512, 256, 0, stream>>>(h1, outdeg, S);
    final_kernel<<<1, 64, 0, stream>>>(S, w_rel3, b_rel3, w_root3, out);
}

// Round 3
// 640.803 us; speedup vs baseline: 1.5980x; 1.4303x over previous
//
#include <hip/hip_runtime.h>

#define N_NODES 100000
#define N_EDGES 1600000
#define F 64
#define SCAN_C 512                          // indeg entries per scan block
#define SCAN_B ((N_NODES + SCAN_C - 1) / SCAN_C)  // 196

// One pass over edges: outdeg[src]++ (for the layer-3 algebraic trick),
// indeg[dst]++ (for CSR row_ptr).
__global__ void degree_kernel(const int* __restrict__ edges,
                              int* __restrict__ outdeg,
                              int* __restrict__ indeg) {
    int e = blockIdx.x * 256 + threadIdx.x;
    if (e < N_EDGES) {
        atomicAdd(&outdeg[edges[e]], 1);
        atomicAdd(&indeg[edges[N_EDGES + e]], 1);
    }
}

// Phase 1: per-block sum of SCAN_C indeg entries (coalesced).
__global__ void bsum_kernel(const int* __restrict__ indeg,
                            int* __restrict__ bsum) {
    __shared__ int red[256];
    int base = blockIdx.x * SCAN_C;
    int i0 = base + threadIdx.x;
    int i1 = i0 + 256;
    int v = 0;
    if (i0 < N_NODES) v += indeg[i0];
    if (i1 < N_NODES) v += indeg[i1];
    red[threadIdx.x] = v;
    __syncthreads();
    for (int off = 128; off > 0; off >>= 1) {
        if (threadIdx.x < off) red[threadIdx.x] += red[threadIdx.x + off];
        __syncthreads();
    }
    if (threadIdx.x == 0) bsum[blockIdx.x] = red[0];
}

// Phase 2: single small block scans the 196 partials (exclusive), writes total.
__global__ void bscan_kernel(const int* __restrict__ bsum,
                             int* __restrict__ boff,
                             int* __restrict__ row_ptr) {
    __shared__ int s[256];
    int tid = threadIdx.x;
    int v = (tid < SCAN_B) ? bsum[tid] : 0;
    s[tid] = v;
    __syncthreads();
    for (int off = 1; off < 256; off <<= 1) {
        int t = (tid >= off) ? s[tid - off] : 0;
        __syncthreads();
        s[tid] += t;
        __syncthreads();
    }
    if (tid < SCAN_B) boff[tid] = s[tid] - v;  // exclusive
    if (tid == 255) row_ptr[N_NODES] = s[255]; // total (== N_EDGES)
}

// Phase 3: block-local exclusive scan of the chunk + block offset ->
// row_ptr / cursor.
__global__ void rowptr_kernel(const int* __restrict__ indeg,
                              const int* __restrict__ boff,
                              int* __restrict__ row_ptr,
                              int* __restrict__ cursor) {
    __shared__ int s[SCAN_C];
    int base = blockIdx.x * SCAN_C;
    int tid = threadIdx.x;
    int i0 = base + tid;
    int i1 = i0 + 256;
    int v0 = (i0 < N_NODES) ? indeg[i0] : 0;
    int v1 = (i1 < N_NODES) ? indeg[i1] : 0;
    s[tid] = v0;
    s[tid + 256] = v1;
    __syncthreads();
    // Hillis-Steele inclusive scan over SCAN_C entries, 256 threads x 2
    for (int off = 1; off < SCAN_C; off <<= 1) {
        int a = (tid >= off) ? s[tid - off] : 0;
        int b = (tid + 256 >= off) ? s[tid + 256 - off] : 0;
        __syncthreads();
        s[tid] += a;
        s[tid + 256] += b;
        __syncthreads();
    }
    int off0 = boff[blockIdx.x];
    if (i0 < N_NODES) {
        int r = off0 + s[tid] - v0;  // exclusive
        row_ptr[i0] = r;
        cursor[i0] = r;
    }
    if (i1 < N_NODES) {
        int r = off0 + s[tid + 256] - v1;
        row_ptr[i1] = r;
        cursor[i1] = r;
    }
}

// col[pos] = src, grouped by dst via atomic cursors. Order within a row is
// arbitrary — fine for a sum.
__global__ void fill_kernel(const int* __restrict__ edges,
                            int* __restrict__ cursor,
                            int* __restrict__ col) {
    int e = blockIdx.x * 256 + threadIdx.x;
    if (e < N_EDGES) {
        int s = edges[e];
        int d = edges[N_EDGES + e];
        int pos = atomicAdd(&cursor[d], 1);
        col[pos] = s;
    }
}

// Atomic-free pull gather: wave-per-node, lane = feature.
// col[e] loads are wave-broadcast (same address); feat row reads are 256B
// coalesced. 4-edge unroll for MLP on the random row fetches.
__global__ void gather_kernel(const float* __restrict__ feat,
                              const int* __restrict__ row_ptr,
                              const int* __restrict__ col,
                              float* __restrict__ aggr) {
    int node = blockIdx.x * 4 + (threadIdx.x >> 6);
    int f = threadIdx.x & 63;
    if (node >= N_NODES) return;
    int beg = row_ptr[node];
    int end = row_ptr[node + 1];
    float acc = 0.f;
    int e = beg;
    for (; e + 3 < end; e += 4) {
        int s0 = col[e];
        int s1 = col[e + 1];
        int s2 = col[e + 2];
        int s3 = col[e + 3];
        float v0 = feat[(size_t)s0 * F + f];
        float v1 = feat[(size_t)s1 * F + f];
        float v2 = feat[(size_t)s2 * F + f];
        float v3 = feat[(size_t)s3 * F + f];
        acc += v0 + v1 + v2 + v3;
    }
    for (; e < end; e++) acc += feat[(size_t)col[e] * F + f];
    aggr[(size_t)node * F + f] = acc;
}

// Fused per-node transform: out = [relu](aggr @ w_rel + b_rel + x @ w_root)
// Row-local per block => out may alias xin (in-place) safely.
__global__ void transform_kernel(const float* __restrict__ aggr,
                                 const float* __restrict__ xin,
                                 const float* __restrict__ w_rel,
                                 const float* __restrict__ b_rel,
                                 const float* __restrict__ w_root,
                                 float* __restrict__ out,
                                 const int do_relu) {
    __shared__ float sA[64 * F];
    __shared__ float sX[64 * F];
    const int node0 = blockIdx.x * 64;
    float4* s4A = (float4*)sA;
    float4* s4X = (float4*)sX;
    const float4* gA = (const float4*)(aggr + (size_t)node0 * F);
    const float4* gX = (const float4*)(xin + (size_t)node0 * F);
    for (int k = threadIdx.x; k < 64 * F / 4; k += 256) {
        int node = node0 + (k >> 4);
        float4 a = make_float4(0.f, 0.f, 0.f, 0.f);
        float4 x = a;
        if (node < N_NODES) { a = gA[k]; x = gX[k]; }
        s4A[k] = a;
        s4X[k] = x;
    }
    __syncthreads();

    const int fp = threadIdx.x & 63;   // output feature
    const int grp = threadIdx.x >> 6;  // node sub-group 0..3
    float acc[16];
    const float bias = b_rel[fp];
#pragma unroll
    for (int k = 0; k < 16; k++) acc[k] = bias;

    for (int f = 0; f < F; f += 4) {
        float wr0 = w_rel[(f + 0) * F + fp];
        float wr1 = w_rel[(f + 1) * F + fp];
        float wr2 = w_rel[(f + 2) * F + fp];
        float wr3 = w_rel[(f + 3) * F + fp];
        float wo0 = w_root[(f + 0) * F + fp];
        float wo1 = w_root[(f + 1) * F + fp];
        float wo2 = w_root[(f + 2) * F + fp];
        float wo3 = w_root[(f + 3) * F + fp];
#pragma unroll
        for (int k = 0; k < 16; k++) {
            int n = grp * 16 + k;
            float4 a = *(const float4*)&sA[n * F + f];
            float4 x = *(const float4*)&sX[n * F + f];
            acc[k] += a.x * wr0 + a.y * wr1 + a.z * wr2 + a.w * wr3
                    + x.x * wo0 + x.y * wo1 + x.z * wo2 + x.w * wo3;
        }
    }
#pragma unroll
    for (int k = 0; k < 16; k++) {
        int n = grp * 16 + k;
        int node = node0 + n;
        if (node < N_NODES) {
            float v = acc[k];
            if (do_relu) v = fmaxf(v, 0.0f);
            out[(size_t)node * F + fp] = v;
        }
    }
}

// S[0:64]  = sum_i outdeg(i) * h2[i][:]   (layer-3 aggr term)
// S[64:128]= sum_i h2[i][:]               (layer-3 root term)
__global__ void reduce_kernel(const float* __restrict__ h,
                              const int* __restrict__ outdeg,
                              float* __restrict__ S) {
    const int f = threadIdx.x & 63;
    const int grp = threadIdx.x >> 6;
    float a1 = 0.f, a2 = 0.f;
    for (int i = blockIdx.x * 4 + grp; i < N_NODES; i += gridDim.x * 4) {
        float deg = (float)outdeg[i];
        float v = h[(size_t)i * F + f];
        a1 += deg * v;
        a2 += v;
    }
    atomicAdd(&S[f], a1);
    atomicAdd(&S[64 + f], a2);
}

// out = mean_i(h3_i) = (S1 . w_rel3 + S2 . w_root3)/N + b3
__global__ void final_kernel(const float* __restrict__ S,
                             const float* __restrict__ w_rel3,
                             const float* __restrict__ b_rel3,
                             const float* __restrict__ w_root3,
                             float* __restrict__ out) {
    int f = threadIdx.x;  // 64 threads, one wave
    float v = S[f] * w_rel3[f] + S[64 + f] * w_root3[f];
    for (int off = 32; off > 0; off >>= 1) v += __shfl_down(v, off);
    if (f == 0) out[0] = v * (1.0f / (float)N_NODES) + b_rel3[0];
}

extern "C" void kernel_launch(void* const* d_in, const int* in_sizes, int n_in,
                              void* d_out, int out_size, void* d_ws, size_t ws_size,
                              hipStream_t stream) {
    const float* x       = (const float*)d_in[0];
    const int*   edges   = (const int*)d_in[1];   // [2, E]: src row then dst row
    const float* w_rel1  = (const float*)d_in[2];
    const float* b_rel1  = (const float*)d_in[3];
    const float* w_root1 = (const float*)d_in[4];
    const float* w_rel2  = (const float*)d_in[5];
    const float* b_rel2  = (const float*)d_in[6];
    const float* w_root2 = (const float*)d_in[7];
    const float* w_rel3  = (const float*)d_in[8];
    const float* b_rel3  = (const float*)d_in[9];
    const float* w_root3 = (const float*)d_in[10];
    float* out = (float*)d_out;

    const size_t nf = (size_t)N_NODES * F;
    float* aggr   = (float*)d_ws;            // 25.6 MB
    float* h1     = aggr + nf;               // 25.6 MB (layer-2 output in-place)
    float* S      = h1 + nf;                 // 512 B
    int*   outdeg = (int*)(S + 128);         // 0.4 MB
    int*   indeg  = outdeg + N_NODES;        // 0.4 MB
    int*   row_ptr= indeg + N_NODES;         // 0.4 MB
    int*   cursor = row_ptr + N_NODES + 1;   // 0.4 MB
    int*   col    = cursor + N_NODES;        // 6.4 MB
    int*   bsum   = col + N_EDGES;           // 784 B
    int*   boff   = bsum + SCAN_B;           // 784 B

    hipMemsetAsync(S, 0, 128 * sizeof(float), stream);
    hipMemsetAsync(outdeg, 0, N_NODES * sizeof(int), stream);
    hipMemsetAsync(indeg, 0, N_NODES * sizeof(int), stream);

    // CSR build (re-done every call; no cross-call state)
    degree_kernel<<<(N_EDGES + 255) / 256, 256, 0, stream>>>(edges, outdeg, indeg);
    bsum_kernel<<<SCAN_B, 256, 0, stream>>>(indeg, bsum);
    bscan_kernel<<<1, 256, 0, stream>>>(bsum, boff, row_ptr);
    rowptr_kernel<<<SCAN_B, 256, 0, stream>>>(indeg, boff, row_ptr, cursor);
    fill_kernel<<<(N_EDGES + 255) / 256, 256, 0, stream>>>(edges, cursor, col);

    const int gather_blocks = (N_NODES + 3) / 4;

    // layer 1
    gather_kernel<<<gather_blocks, 256, 0, stream>>>(x, row_ptr, col, aggr);
    transform_kernel<<<(N_NODES + 63) / 64, 256, 0, stream>>>(aggr, x, w_rel1, b_rel1, w_root1, h1, 1);

    // layer 2 (transform writes h1 in-place; it's row-local per block)
    gather_kernel<<<gather_blocks, 256, 0, stream>>>(h1, row_ptr, col, aggr);
    transform_kernel<<<(N_NODES + 63) / 64, 256, 0, stream>>>(aggr, h1, w_rel2, b_rel2, w_root2, h1, 1);

    // layer 3 collapsed to reductions
    reduce_kernel<<<512, 256, 0, stream>>>(h1, outdeg, S);
    final_kernel<<<1, 64, 0, stream>>>(S, w_rel3, b_rel3, w_root3, out);
}